// Round 20
// baseline (224.720 us; speedup 1.0000x reference)
//
#include <hip/hip_runtime.h>
#include <hip/hip_bf16.h>

// B=4, S=2048, D=1024, H=16, DH=64
typedef __attribute__((ext_vector_type(4))) float f32x4;
typedef __attribute__((ext_vector_type(8))) short bf16x8;
typedef __attribute__((ext_vector_type(4))) unsigned short u16x4;

#define MFMA16(a, b, c) __builtin_amdgcn_mfma_f32_16x16x32_bf16((a), (b), (c), 0, 0, 0)

static __device__ __forceinline__ unsigned short f2bf(float f) {
    unsigned u = __float_as_uint(f);
    u += 0x7FFFu + ((u >> 16) & 1u);   // RNE
    return (unsigned short)(u >> 16);
}
static __device__ __forceinline__ uint2 pack4_rhu(float4 v) {
    unsigned a = __float_as_uint(v.x) + 0x8000u;
    unsigned b = __float_as_uint(v.y) + 0x8000u;
    unsigned c = __float_as_uint(v.z) + 0x8000u;
    unsigned d = __float_as_uint(v.w) + 0x8000u;
    uint2 r;
    r.x = __builtin_amdgcn_perm(b, a, 0x07060302u);
    r.y = __builtin_amdgcn_perm(d, c, 0x07060302u);
    return r;
}
static __device__ __forceinline__ float bf2f(unsigned v) {
    return __uint_as_float(v << 16);
}
static __device__ __forceinline__ float exp2_fast(float x) {
#if __has_builtin(__builtin_amdgcn_exp2f)
    return __builtin_amdgcn_exp2f(x);
#else
    return exp2f(x);
#endif
}

// scores premultiplied so softmax runs in exp2 domain: c = log2(e)/32
#define QSCALE 0.04508422002778011f

// ---------------- merged prep: qproj (blocks 0..511) + v-trans (512..2559) ----------------
__global__ __launch_bounds__(256) void prep_kernel(const float* __restrict__ x,
                                                   const float* __restrict__ wq,
                                                   const float* __restrict__ vin,
                                                   unsigned short* __restrict__ qout,
                                                   unsigned short* __restrict__ vt) {
    __shared__ __align__(16) unsigned short As[2][128][40];
    __shared__ __align__(16) unsigned short Bs[2][128][40];
    const int bid = blockIdx.x;
    const int tid = threadIdx.x;

    if (bid < 512) {
        const int m0 = (bid & 63) * 128;
        const int n0 = (bid >> 6) * 128;
        const int wave = tid >> 6, lane = tid & 63;
        const int lg = lane >> 4, lc = lane & 15;
        const int wm = wave >> 1, wn = wave & 1;

        f32x4 acc[4][4];
#pragma unroll
        for (int i = 0; i < 4; ++i)
#pragma unroll
            for (int j = 0; j < 4; ++j) acc[i][j] = (f32x4){0.f, 0.f, 0.f, 0.f};

        float4 ax[4], bx[4];
#pragma unroll
        for (int i = 0; i < 4; ++i) {
            int c = tid + i * 256;
            int row = c >> 3, kc = (c & 7) * 4;
            ax[i] = *(const float4*)(x  + (size_t)(m0 + row) * 1024 + kc);
            bx[i] = *(const float4*)(wq + (size_t)(n0 + row) * 1024 + kc);
        }
#pragma unroll
        for (int i = 0; i < 4; ++i) {
            int c = tid + i * 256;
            int row = c >> 3, kc = (c & 7) * 4;
            *(uint2*)&As[0][row][kc] = pack4_rhu(ax[i]);
            *(uint2*)&Bs[0][row][kc] = pack4_rhu(bx[i]);
        }

        int cur = 0;
        for (int ki = 0; ki < 32; ++ki) {
            __syncthreads();
            const bool havenext = (ki + 1 < 32);
            if (havenext) {
                int ks = (ki + 1) * 32;
#pragma unroll
                for (int i = 0; i < 4; ++i) {
                    int c = tid + i * 256;
                    int row = c >> 3, kc = (c & 7) * 4;
                    ax[i] = *(const float4*)(x  + (size_t)(m0 + row) * 1024 + ks + kc);
                    bx[i] = *(const float4*)(wq + (size_t)(n0 + row) * 1024 + ks + kc);
                }
            }
            bf16x8 af[4], bfr[4];
#pragma unroll
            for (int i = 0; i < 4; ++i) {
                af[i]  = *(const bf16x8*)&As[cur][wm * 64 + i * 16 + lc][lg * 8];
                bfr[i] = *(const bf16x8*)&Bs[cur][wn * 64 + i * 16 + lc][lg * 8];
            }
            __builtin_amdgcn_s_setprio(1);
#pragma unroll
            for (int mi = 0; mi < 4; ++mi)
#pragma unroll
                for (int ni = 0; ni < 4; ++ni)
                    acc[mi][ni] = MFMA16(af[mi], bfr[ni], acc[mi][ni]);
            __builtin_amdgcn_s_setprio(0);
            if (havenext) {
#pragma unroll
                for (int i = 0; i < 4; ++i) {
                    int c = tid + i * 256;
                    int row = c >> 3, kc = (c & 7) * 4;
                    *(uint2*)&As[cur ^ 1][row][kc] = pack4_rhu(ax[i]);
                    *(uint2*)&Bs[cur ^ 1][row][kc] = pack4_rhu(bx[i]);
                }
            }
            cur ^= 1;
        }
#pragma unroll
        for (int mi = 0; mi < 4; ++mi)
#pragma unroll
            for (int ni = 0; ni < 4; ++ni)
#pragma unroll
                for (int r = 0; r < 4; ++r) {
                    int m = m0 + wm * 64 + mi * 16 + lg * 4 + r;
                    int n = n0 + wn * 64 + ni * 16 + lc;
                    int b = m >> 11, s = m & 2047;
                    int h = n >> 6, dh = n & 63;
                    qout[(((size_t)b * 16 + h) * 2048 + s) * 64 + dh] = f2bf(acc[mi][ni][r] * QSCALE);
                }
    } else {
        // v fp32 [B,H,S,DH] -> bf16 [B,H,DH,S]
        float (*buf)[65] = (float (*)[65])(&As[0][0][0]);
        const int idx = bid - 512;
        const int s0 = (idx & 31) * 64;
        const int bh = idx >> 5;
#pragma unroll
        for (int i = 0; i < 4; ++i) {
            int c = tid + i * 256;
            int s = c >> 4, dc = (c & 15) * 4;
            float4 val = *(const float4*)(vin + ((size_t)bh * 2048 + s0 + s) * 64 + dc);
            buf[s][dc] = val.x; buf[s][dc + 1] = val.y; buf[s][dc + 2] = val.z; buf[s][dc + 3] = val.w;
        }
        __syncthreads();
#pragma unroll
        for (int i = 0; i < 4; ++i) {
            int c = tid + i * 256;
            int dh = c >> 4, sc = (c & 15) * 4;
            u16x4 o = { f2bf(buf[sc][dh]), f2bf(buf[sc + 1][dh]), f2bf(buf[sc + 2][dh]), f2bf(buf[sc + 3][dh]) };
            *(u16x4*)(vt + ((size_t)bh * 64 + dh) * 2048 + s0 + sc) = o;
        }
    }
}

// ---------------- fused causal flash attention + residual, kv-split ----------------
// grid: (64 bh, 24 tasks), task table descending-work (LPT). qb>=8 split into two
// equal kv-halves (qb+1 iters each); fixed-max exp2 softmax makes partials combine
// by PURE ADDITION: O=(O1+O2)/(l1+l2). Ticket merge via device atomics+fences
// (partner halves share bh -> same XCD L2). 256 thr (4 waves x 32 q-rows).
// SINGLE-buffered K/VT (2 barriers/iter) + XOR-swizzled Ps[4][32][64] = 32KB LDS
// -> 5 blocks/CU = 1280 slots < 1536 blocks = real backfill queue.
// K staged directly from fp32. Swapped QK^T & PV; deferred l; vec4 epilogue.
__global__ __launch_bounds__(256) void attn_kernel(const unsigned short* __restrict__ qg,
                                                   const float* __restrict__ kg32,
                                                   const unsigned short* __restrict__ vtg,
                                                   const float* __restrict__ x,
                                                   float* __restrict__ outp,
                                                   unsigned short* __restrict__ Opart,
                                                   float* __restrict__ lpart,
                                                   unsigned int* __restrict__ tickets) {
    __shared__ __align__(16) unsigned short Ks[64][64];
    __shared__ __align__(16) unsigned short VTs[64][64];
    __shared__ __align__(16) unsigned short Ps[4][32][64];

    // task table: code = (qb<<2) | (split<<1) | half, descending work order
    static const unsigned char tab[24] = {
        62, 63, 28, 58, 59, 54, 55, 24, 50, 51, 46, 47,
        20, 42, 43, 38, 39, 16, 34, 35, 12, 8, 4, 0
    };
    const unsigned code = tab[blockIdx.y];
    const int qb = code >> 2;
    const int split = (code >> 1) & 1;
    const int half = code & 1;
    const int kv0 = (split && half) ? (qb + 1) : 0;
    const int kv1 = split ? (half ? (2 * qb + 2) : (qb + 1)) : (2 * qb + 2);

    const int bh = blockIdx.x;
    const int b = bh >> 4, h = bh & 15;
    const int tid = threadIdx.x;
    const int wave = tid >> 6, lane = tid & 63;
    const int lg = lane >> 4, lc = lane & 15;
    const int lc7 = lc & 7;
    const int qw0 = qb * 128 + wave * 32;

    // staging: 256 threads cover 512 chunks of K and VT (2 rows each, same c16)
    const int r0  = tid >> 3;            // 0..31
    const int c16 = tid & 7;
    const int swz = (c16 ^ (r0 & 7)) * 8;
    const float* kbase = kg32 + ((size_t)bh * 2048 + r0) * 64 + c16 * 8;
    const unsigned short* vbase = vtg + ((size_t)bh * 64 + r0) * 2048 + c16 * 8;

    // Q B-frags in registers
    bf16x8 qf[2][2];
#pragma unroll
    for (int qt = 0; qt < 2; ++qt)
#pragma unroll
        for (int c = 0; c < 2; ++c)
            qf[qt][c] = *(const bf16x8*)(qg + ((size_t)bh * 2048 + qw0 + qt * 16 + lc) * 64 + c * 32 + lg * 8);

    f32x4 oacc[2][4];   // O^T: col=lc=q-local, row=lg*4+r=dh-local
#pragma unroll
    for (int qt = 0; qt < 2; ++qt)
#pragma unroll
        for (int dt = 0; dt < 4; ++dt) oacc[qt][dt] = (f32x4){0.f, 0.f, 0.f, 0.f};
    float l_r[2] = {0.f, 0.f};

    {   // prologue: stage tile kv0
        union { uint2 u[2]; bf16x8 v; } cka, ckb;
        cka.u[0] = pack4_rhu(*(const float4*)(kbase + (size_t)kv0 * 4096));
        cka.u[1] = pack4_rhu(*(const float4*)(kbase + (size_t)kv0 * 4096 + 4));
        ckb.u[0] = pack4_rhu(*(const float4*)(kbase + (size_t)kv0 * 4096 + 2048));
        ckb.u[1] = pack4_rhu(*(const float4*)(kbase + (size_t)kv0 * 4096 + 2052));
        *(bf16x8*)&Ks[r0][swz]       = cka.v;
        *(bf16x8*)&Ks[r0 + 32][swz]  = ckb.v;
        *(bf16x8*)&VTs[r0][swz]      = *(const bf16x8*)(vbase + kv0 * 64);
        *(bf16x8*)&VTs[r0 + 32][swz] = *(const bf16x8*)(vbase + kv0 * 64 + 65536);
    }

    for (int kv = kv0; kv < kv1; ++kv) {
        __syncthreads();   // tile kv staged & visible

        const bool havenext = (kv + 1 < kv1);
        const int nxt = havenext ? kv + 1 : kv;
        float4 nka0 = *(const float4*)(kbase + (size_t)nxt * 4096);
        float4 nka1 = *(const float4*)(kbase + (size_t)nxt * 4096 + 4);
        float4 nkb0 = *(const float4*)(kbase + (size_t)nxt * 4096 + 2048);
        float4 nkb1 = *(const float4*)(kbase + (size_t)nxt * 4096 + 2052);
        bf16x8 nv0 = *(const bf16x8*)(vbase + nxt * 64);
        bf16x8 nv1 = *(const bf16x8*)(vbase + nxt * 64 + 65536);

        const bool active = (kv * 64 <= qw0 + 31);
        if (active) {
            bf16x8 kf[4][2];
#pragma unroll
            for (int kt = 0; kt < 4; ++kt)
#pragma unroll
                for (int c = 0; c < 2; ++c)
                    kf[kt][c] = *(const bf16x8*)&Ks[kt * 16 + lc][((4 * c + lg) ^ lc7) * 8];

            const int kvb = kv * 64;
#pragma unroll
            for (int qt = 0; qt < 2; ++qt) {
                f32x4 st[4];
                __builtin_amdgcn_s_setprio(1);
#pragma unroll
                for (int kt = 0; kt < 4; ++kt) {
                    f32x4 a = (f32x4){0.f, 0.f, 0.f, 0.f};
                    a = MFMA16(kf[kt][0], qf[qt][0], a);
                    a = MFMA16(kf[kt][1], qf[qt][1], a);
                    st[kt] = a;
                }
                __builtin_amdgcn_s_setprio(0);

                float pp[4][4];
#pragma unroll
                for (int kt = 0; kt < 4; ++kt)
#pragma unroll
                    for (int r = 0; r < 4; ++r) pp[kt][r] = st[kt][r];
                if (kvb + 63 > qw0 + qt * 16) {   // diagonal tile only
                    const int qrow = qw0 + qt * 16 + lc;
#pragma unroll
                    for (int kt = 0; kt < 4; ++kt)
#pragma unroll
                        for (int r = 0; r < 4; ++r) {
                            int kk = kvb + kt * 16 + lg * 4 + r;
                            if (kk > qrow) pp[kt][r] = -1e30f;
                        }
                }
                float rs = 0.f;
#pragma unroll
                for (int kt = 0; kt < 4; ++kt)
#pragma unroll
                    for (int r = 0; r < 4; ++r) {
                        float e = exp2_fast(pp[kt][r]);
                        pp[kt][r] = e;
                        rs += e;
                    }
                l_r[qt] += rs;
                // Ps write, chunk-XOR-swizzled: logical col kt*16+lg*4 -> chunk kt*2+(lg>>1)
#pragma unroll
                for (int kt = 0; kt < 4; ++kt) {
                    uint2 w;
                    w.x = __builtin_amdgcn_perm(__float_as_uint(pp[kt][1]), __float_as_uint(pp[kt][0]), 0x07060302u);
                    w.y = __builtin_amdgcn_perm(__float_as_uint(pp[kt][3]), __float_as_uint(pp[kt][2]), 0x07060302u);
                    *(uint2*)&Ps[wave][qt * 16 + lc][((kt * 2 + (lg >> 1)) ^ lc7) * 8 + (lg & 1) * 4] = w;
                }
            }
            asm volatile("s_waitcnt lgkmcnt(0)" ::: "memory");

            // O^T += V^T P^T : pf read swizzled (logical chunk c*4+lg)
            bf16x8 pf[2][2];
#pragma unroll
            for (int qt = 0; qt < 2; ++qt)
#pragma unroll
                for (int c = 0; c < 2; ++c)
                    pf[qt][c] = *(const bf16x8*)&Ps[wave][qt * 16 + lc][((c * 4 + lg) ^ lc7) * 8];
            __builtin_amdgcn_s_setprio(1);
#pragma unroll
            for (int dt = 0; dt < 4; ++dt)
#pragma unroll
                for (int c = 0; c < 2; ++c) {
                    bf16x8 vtf = *(const bf16x8*)&VTs[dt * 16 + lc][((4 * c + lg) ^ lc7) * 8];
#pragma unroll
                    for (int qt = 0; qt < 2; ++qt)
                        oacc[qt][dt] = MFMA16(vtf, pf[qt][c], oacc[qt][dt]);
                }
            __builtin_amdgcn_s_setprio(0);
        }

        __syncthreads();   // all reads of tile kv done
        if (havenext) {
            union { uint2 u[2]; bf16x8 v; } cka, ckb;
            cka.u[0] = pack4_rhu(nka0);
            cka.u[1] = pack4_rhu(nka1);
            ckb.u[0] = pack4_rhu(nkb0);
            ckb.u[1] = pack4_rhu(nkb1);
            *(bf16x8*)&Ks[r0][swz]       = cka.v;
            *(bf16x8*)&Ks[r0 + 32][swz]  = ckb.v;
            *(bf16x8*)&VTs[r0][swz]      = nv0;
            *(bf16x8*)&VTs[r0 + 32][swz] = nv1;
        }
    }

    // finish l reduction (all lanes end with the full row sum)
    float lt[2];
#pragma unroll
    for (int qt = 0; qt < 2; ++qt) {
        float t = l_r[qt];
        t += __shfl_xor(t, 16, 64);
        t += __shfl_xor(t, 32, 64);
        lt[qt] = t;
    }

    if (!split) {
        // direct epilogue
#pragma unroll
        for (int qt = 0; qt < 2; ++qt) {
            float li = 1.0f / lt[qt];
            const int q = qw0 + qt * 16 + lc;
            const size_t obase = ((size_t)b * 2048 + q) * 1024 + (size_t)h * 64 + lg * 4;
#pragma unroll
            for (int dt = 0; dt < 4; ++dt) {
                const size_t oi = obase + dt * 16;
                float4 xv = *(const float4*)(x + oi);
                float4 ov;
                ov.x = xv.x + oacc[qt][dt][0] * li;
                ov.y = xv.y + oacc[qt][dt][1] * li;
                ov.z = xv.z + oacc[qt][dt][2] * li;
                ov.w = xv.w + oacc[qt][dt][3] * li;
                *(float4*)(outp + oi) = ov;
            }
        }
    } else {
        const int p = bh * 8 + (qb - 8);
        // pack own partial O to bf16 (also the merge operand -> deterministic)
        uint2 wk[2][4];
#pragma unroll
        for (int qt = 0; qt < 2; ++qt)
#pragma unroll
            for (int dt = 0; dt < 4; ++dt) {
                float4 v = make_float4(oacc[qt][dt][0], oacc[qt][dt][1], oacc[qt][dt][2], oacc[qt][dt][3]);
                wk[qt][dt] = pack4_rhu(v);
            }
        unsigned short* slot = Opart + ((size_t)(half * 512 + p)) * 8192 + tid * 32;
#pragma unroll
        for (int qt = 0; qt < 2; ++qt)
#pragma unroll
            for (int dt = 0; dt < 4; ++dt)
                *(uint2*)(slot + (qt * 4 + dt) * 4) = wk[qt][dt];
        float* lsl = lpart + ((size_t)(half * 512 + p)) * 512 + tid * 2;
        lsl[0] = lt[0];
        lsl[1] = lt[1];
        __syncthreads();
        int* flagp = (int*)&Ps[0][0][0];
        if (tid == 0) {
            __threadfence();                         // release own partial
            unsigned old = atomicAdd(&tickets[p], 1u);
            *flagp = (int)old;
        }
        __syncthreads();
        if (*flagp == 0) return;                     // first finisher: partial stored
        __threadfence();                             // acquire partner partial
        const unsigned short* pslot = Opart + ((size_t)((1 - half) * 512 + p)) * 8192 + tid * 32;
        const float* plsl = lpart + ((size_t)((1 - half) * 512 + p)) * 512 + tid * 2;
        float li[2];
        li[0] = 1.0f / (lt[0] + plsl[0]);
        li[1] = 1.0f / (lt[1] + plsl[1]);
#pragma unroll
        for (int qt = 0; qt < 2; ++qt) {
            const int q = qw0 + qt * 16 + lc;
            const size_t obase = ((size_t)b * 2048 + q) * 1024 + (size_t)h * 64 + lg * 4;
#pragma unroll
            for (int dt = 0; dt < 4; ++dt) {
                uint2 pw = *(const uint2*)(pslot + (qt * 4 + dt) * 4);
                uint2 ow = wk[qt][dt];
                float4 f;
                f.x = bf2f(ow.x & 0xffffu) + bf2f(pw.x & 0xffffu);
                f.y = bf2f(ow.x >> 16)     + bf2f(pw.x >> 16);
                f.z = bf2f(ow.y & 0xffffu) + bf2f(pw.y & 0xffffu);
                f.w = bf2f(ow.y >> 16)     + bf2f(pw.y >> 16);
                const size_t oi = obase + dt * 16;
                float4 xv = *(const float4*)(x + oi);
                float4 ov;
                ov.x = xv.x + f.x * li[qt];
                ov.y = xv.y + f.y * li[qt];
                ov.z = xv.z + f.z * li[qt];
                ov.w = xv.w + f.w * li[qt];
                *(float4*)(outp + oi) = ov;
            }
        }
    }
}

extern "C" void kernel_launch(void* const* d_in, const int* in_sizes, int n_in,
                              void* d_out, int out_size, void* d_ws, size_t ws_size,
                              hipStream_t stream) {
    const float* x  = (const float*)d_in[0];
    const float* k  = (const float*)d_in[1];
    const float* v  = (const float*)d_in[2];
    const float* wq = (const float*)d_in[3];
    float* outp = (float*)d_out;

    const size_t NELEM = (size_t)4 * 2048 * 1024;   // 8,388,608
    unsigned short* qbuf  = (unsigned short*)d_ws;
    unsigned short* vtbuf = qbuf + NELEM;
    unsigned short* Opart = vtbuf + NELEM;          // 2*512*8192 u16 = 16MB
    float* lpart = (float*)(Opart + (size_t)2 * 512 * 8192);   // 2*512*512 f32 = 2MB
    unsigned int* tickets = (unsigned int*)(lpart + (size_t)2 * 512 * 512);  // 512 u32

    hipMemsetAsync(tickets, 0, 512 * sizeof(unsigned int), stream);
    prep_kernel<<<512 + 2048, 256, 0, stream>>>(x, wq, v, qbuf, vtbuf);
    attn_kernel<<<dim3(64, 24), 256, 0, stream>>>(qbuf, k, vtbuf, x, outp,
                                                  Opart, lpart, tickets);
}

// Round 21
// 91.677 us; speedup vs baseline: 2.4512x; 2.4512x over previous
//
#include <hip/hip_runtime.h>
#include <hip/hip_bf16.h>

// B=4, S=2048, D=1024, H=16, DH=64
typedef __attribute__((ext_vector_type(4))) float f32x4;
typedef __attribute__((ext_vector_type(8))) short bf16x8;
typedef __attribute__((ext_vector_type(4))) unsigned short u16x4;

#define MFMA16(a, b, c) __builtin_amdgcn_mfma_f32_16x16x32_bf16((a), (b), (c), 0, 0, 0)

static __device__ __forceinline__ unsigned short f2bf(float f) {
    unsigned u = __float_as_uint(f);
    u += 0x7FFFu + ((u >> 16) & 1u);   // RNE
    return (unsigned short)(u >> 16);
}
// pack 4 floats -> 4 bf16 (round-half-up) as uint2, via v_perm_b32
static __device__ __forceinline__ uint2 pack4_rhu(float4 v) {
    unsigned a = __float_as_uint(v.x) + 0x8000u;
    unsigned b = __float_as_uint(v.y) + 0x8000u;
    unsigned c = __float_as_uint(v.z) + 0x8000u;
    unsigned d = __float_as_uint(v.w) + 0x8000u;
    uint2 r;
    r.x = __builtin_amdgcn_perm(b, a, 0x07060302u);
    r.y = __builtin_amdgcn_perm(d, c, 0x07060302u);
    return r;
}
static __device__ __forceinline__ float exp2_fast(float x) {
#if __has_builtin(__builtin_amdgcn_exp2f)
    return __builtin_amdgcn_exp2f(x);
#else
    return exp2f(x);
#endif
}

// scores premultiplied so softmax runs in exp2 domain: c = log2(e)/32
#define QSCALE 0.04508422002778011f

// ---------------- merged prep: qproj (blocks 0..511) + v-trans (512..2559) ----------------
// k-conversion ELIMINATED: attn stages K directly from fp32 (saves 48MB HBM).
__global__ __launch_bounds__(256) void prep_kernel(const float* __restrict__ x,
                                                   const float* __restrict__ wq,
                                                   const float* __restrict__ vin,
                                                   unsigned short* __restrict__ qout,
                                                   unsigned short* __restrict__ vt) {
    __shared__ __align__(16) unsigned short As[2][128][40];   // 20KB (reused by v-trans)
    __shared__ __align__(16) unsigned short Bs[2][128][40];   // 20KB
    const int bid = blockIdx.x;
    const int tid = threadIdx.x;

    if (bid < 512) {
        // ---------------- Q projection: q = (x @ Wq^T) * QSCALE, bf16 [B,H,S,DH] ----------------
        const int m0 = (bid & 63) * 128;
        const int n0 = (bid >> 6) * 128;
        const int wave = tid >> 6, lane = tid & 63;
        const int lg = lane >> 4, lc = lane & 15;
        const int wm = wave >> 1, wn = wave & 1;

        f32x4 acc[4][4];
#pragma unroll
        for (int i = 0; i < 4; ++i)
#pragma unroll
            for (int j = 0; j < 4; ++j) acc[i][j] = (f32x4){0.f, 0.f, 0.f, 0.f};

        float4 ax[4], bx[4];
#pragma unroll
        for (int i = 0; i < 4; ++i) {
            int c = tid + i * 256;
            int row = c >> 3, kc = (c & 7) * 4;
            ax[i] = *(const float4*)(x  + (size_t)(m0 + row) * 1024 + kc);
            bx[i] = *(const float4*)(wq + (size_t)(n0 + row) * 1024 + kc);
        }
#pragma unroll
        for (int i = 0; i < 4; ++i) {
            int c = tid + i * 256;
            int row = c >> 3, kc = (c & 7) * 4;
            *(uint2*)&As[0][row][kc] = pack4_rhu(ax[i]);
            *(uint2*)&Bs[0][row][kc] = pack4_rhu(bx[i]);
        }

        int cur = 0;
        for (int ki = 0; ki < 32; ++ki) {
            __syncthreads();
            const bool havenext = (ki + 1 < 32);
            if (havenext) {
                int ks = (ki + 1) * 32;
#pragma unroll
                for (int i = 0; i < 4; ++i) {
                    int c = tid + i * 256;
                    int row = c >> 3, kc = (c & 7) * 4;
                    ax[i] = *(const float4*)(x  + (size_t)(m0 + row) * 1024 + ks + kc);
                    bx[i] = *(const float4*)(wq + (size_t)(n0 + row) * 1024 + ks + kc);
                }
            }
            bf16x8 af[4], bfr[4];
#pragma unroll
            for (int i = 0; i < 4; ++i) {
                af[i]  = *(const bf16x8*)&As[cur][wm * 64 + i * 16 + lc][lg * 8];
                bfr[i] = *(const bf16x8*)&Bs[cur][wn * 64 + i * 16 + lc][lg * 8];
            }
            __builtin_amdgcn_s_setprio(1);
#pragma unroll
            for (int mi = 0; mi < 4; ++mi)
#pragma unroll
                for (int ni = 0; ni < 4; ++ni)
                    acc[mi][ni] = MFMA16(af[mi], bfr[ni], acc[mi][ni]);
            __builtin_amdgcn_s_setprio(0);
            if (havenext) {
#pragma unroll
                for (int i = 0; i < 4; ++i) {
                    int c = tid + i * 256;
                    int row = c >> 3, kc = (c & 7) * 4;
                    *(uint2*)&As[cur ^ 1][row][kc] = pack4_rhu(ax[i]);
                    *(uint2*)&Bs[cur ^ 1][row][kc] = pack4_rhu(bx[i]);
                }
            }
            cur ^= 1;
        }
#pragma unroll
        for (int mi = 0; mi < 4; ++mi)
#pragma unroll
            for (int ni = 0; ni < 4; ++ni)
#pragma unroll
                for (int r = 0; r < 4; ++r) {
                    int m = m0 + wm * 64 + mi * 16 + lg * 4 + r;
                    int n = n0 + wn * 64 + ni * 16 + lc;
                    int b = m >> 11, s = m & 2047;
                    int h = n >> 6, dh = n & 63;
                    qout[(((size_t)b * 16 + h) * 2048 + s) * 64 + dh] = f2bf(acc[mi][ni][r] * QSCALE);
                }
    } else {
        // ---------------- v fp32 [B,H,S,DH] -> bf16 [B,H,DH,S] ----------------
        float (*buf)[65] = (float (*)[65])(&As[0][0][0]);   // 16.6KB, fits in As
        const int idx = bid - 512;
        const int s0 = (idx & 31) * 64;
        const int bh = idx >> 5;
#pragma unroll
        for (int i = 0; i < 4; ++i) {
            int c = tid + i * 256;
            int s = c >> 4, dc = (c & 15) * 4;
            float4 val = *(const float4*)(vin + ((size_t)bh * 2048 + s0 + s) * 64 + dc);
            buf[s][dc] = val.x; buf[s][dc + 1] = val.y; buf[s][dc + 2] = val.z; buf[s][dc + 3] = val.w;
        }
        __syncthreads();
#pragma unroll
        for (int i = 0; i < 4; ++i) {
            int c = tid + i * 256;
            int dh = c >> 4, sc = (c & 15) * 4;
            u16x4 o = { f2bf(buf[sc][dh]), f2bf(buf[sc + 1][dh]), f2bf(buf[sc + 2][dh]), f2bf(buf[sc + 3][dh]) };
            *(u16x4*)(vt + ((size_t)bh * 64 + dh) * 2048 + s0 + sc) = o;
        }
    }
}

// ---------------- fused causal flash attention + residual (R10 body + fp32-K staging) ----------------
// grid: (64 bh, 16), qb = 15 - blockIdx.y -> LPT dispatch (longest first, x fastest).
// 256 threads (4 waves) x 32 q-rows = one 128-row q-block per block.
// LDS 51KB -> 3 blocks/CU: 768 slots < 1024 blocks = real backfill queue.
// K staged DIRECTLY from fp32 input (pack4_rhu at ds_write time; loads still
// issued before compute -> async-split preserved). Ps padded to 76 (conflict-free).
// Swapped QK^T & PV; no-max exp2 softmax; deferred l-reduction; vec4 epilogue.
__global__ __launch_bounds__(256, 3) void attn_kernel(const unsigned short* __restrict__ qg,
                                                      const float* __restrict__ kg32,
                                                      const unsigned short* __restrict__ vtg,
                                                      const float* __restrict__ x,
                                                      float* __restrict__ outp) {
    __shared__ __align__(16) unsigned short Ks[2][64][64];
    __shared__ __align__(16) unsigned short VTs[2][64][64];
    __shared__ __align__(16) unsigned short Ps[4][32][76];

    const int bh = blockIdx.x;
    const int qb = 15 - blockIdx.y;
    const int b = bh >> 4, h = bh & 15;
    const int tid = threadIdx.x;
    const int wave = tid >> 6, lane = tid & 63;
    const int lg = lane >> 4, lc = lane & 15;
    const int lc7 = lc & 7;
    const int qw0 = qb * 128 + wave * 32;
    const int nkv = 2 * qb + 2;

    // staging: 256 threads cover 512 chunks of K and VT (2 rows each, same c16)
    const int r0  = tid >> 3;            // 0..31
    const int c16 = tid & 7;
    const int swz = (c16 ^ (r0 & 7)) * 8;    // same for r0+32 (low 3 bits equal)
    const float* kbase = kg32 + ((size_t)bh * 2048 + r0) * 64 + c16 * 8;
    const unsigned short* vbase = vtg + ((size_t)bh * 64 + r0) * 2048 + c16 * 8;

    // Q B-frags in registers: qf[qt][c] = Q[qw0+qt*16+lc][c*32 + lg*8 ..]
    bf16x8 qf[2][2];
#pragma unroll
    for (int qt = 0; qt < 2; ++qt)
#pragma unroll
        for (int c = 0; c < 2; ++c)
            qf[qt][c] = *(const bf16x8*)(qg + ((size_t)bh * 2048 + qw0 + qt * 16 + lc) * 64 + c * 32 + lg * 8);

    f32x4 oacc[2][4];   // O^T: col=lc=q-local, row=lg*4+r=dh-local
#pragma unroll
    for (int qt = 0; qt < 2; ++qt)
#pragma unroll
        for (int dt = 0; dt < 4; ++dt) oacc[qt][dt] = (f32x4){0.f, 0.f, 0.f, 0.f};
    float l_r[2] = {0.f, 0.f};   // lane-local partials; cross-group reduce in epilogue

    {   // prologue: stage tile 0 into buffer 0 (K converted fp32->bf16 here)
        union { uint2 u[2]; bf16x8 v; } cka, ckb;
        cka.u[0] = pack4_rhu(*(const float4*)(kbase));
        cka.u[1] = pack4_rhu(*(const float4*)(kbase + 4));
        ckb.u[0] = pack4_rhu(*(const float4*)(kbase + 2048));
        ckb.u[1] = pack4_rhu(*(const float4*)(kbase + 2052));
        *(bf16x8*)&Ks[0][r0][swz]       = cka.v;
        *(bf16x8*)&Ks[0][r0 + 32][swz]  = ckb.v;
        *(bf16x8*)&VTs[0][r0][swz]      = *(const bf16x8*)(vbase);
        *(bf16x8*)&VTs[0][r0 + 32][swz] = *(const bf16x8*)(vbase + 65536);
    }

    int cur = 0;
    for (int kv = 0; kv < nkv; ++kv) {
        __syncthreads();   // buf[cur] staged & visible; buf[cur^1] readers done

        const bool havenext = (kv + 1 < nkv);
        const int nxt = havenext ? kv + 1 : kv;
        // issue next-tile loads early (latency hides under compute)
        float4 nka0 = *(const float4*)(kbase + (size_t)nxt * 4096);
        float4 nka1 = *(const float4*)(kbase + (size_t)nxt * 4096 + 4);
        float4 nkb0 = *(const float4*)(kbase + (size_t)nxt * 4096 + 2048);
        float4 nkb1 = *(const float4*)(kbase + (size_t)nxt * 4096 + 2052);
        bf16x8 nv0 = *(const bf16x8*)(vbase + nxt * 64);
        bf16x8 nv1 = *(const bf16x8*)(vbase + nxt * 64 + 65536);

        const bool active = (kv * 64 <= qw0 + 31);
        if (active) {
            // K A-frags (shared across both q-tiles)
            bf16x8 kf[4][2];
#pragma unroll
            for (int kt = 0; kt < 4; ++kt)
#pragma unroll
                for (int c = 0; c < 2; ++c)
                    kf[kt][c] = *(const bf16x8*)&Ks[cur][kt * 16 + lc][((4 * c + lg) ^ lc7) * 8];

            const int kvb = kv * 64;
            // ---- per q-tile: S^T = K Q^T (8 MFMA), softmax, pack -> Ps ----
#pragma unroll
            for (int qt = 0; qt < 2; ++qt) {
                f32x4 st[4];
                __builtin_amdgcn_s_setprio(1);
#pragma unroll
                for (int kt = 0; kt < 4; ++kt) {
                    f32x4 a = (f32x4){0.f, 0.f, 0.f, 0.f};
                    a = MFMA16(kf[kt][0], qf[qt][0], a);
                    a = MFMA16(kf[kt][1], qf[qt][1], a);
                    st[kt] = a;
                }
                __builtin_amdgcn_s_setprio(0);

                float pp[4][4];
#pragma unroll
                for (int kt = 0; kt < 4; ++kt)
#pragma unroll
                    for (int r = 0; r < 4; ++r) pp[kt][r] = st[kt][r];
                if (kvb + 63 > qw0 + qt * 16) {   // diagonal tile only
                    const int qrow = qw0 + qt * 16 + lc;
#pragma unroll
                    for (int kt = 0; kt < 4; ++kt)
#pragma unroll
                        for (int r = 0; r < 4; ++r) {
                            int kk = kvb + kt * 16 + lg * 4 + r;
                            if (kk > qrow) pp[kt][r] = -1e30f;
                        }
                }
                float rs = 0.f;
#pragma unroll
                for (int kt = 0; kt < 4; ++kt)
#pragma unroll
                    for (int r = 0; r < 4; ++r) {
                        float e = exp2_fast(pp[kt][r]);
                        pp[kt][r] = e;
                        rs += e;
                    }
                l_r[qt] += rs;
#pragma unroll
                for (int kt = 0; kt < 4; ++kt) {
                    uint2 w;
                    w.x = __builtin_amdgcn_perm(__float_as_uint(pp[kt][1]), __float_as_uint(pp[kt][0]), 0x07060302u);
                    w.y = __builtin_amdgcn_perm(__float_as_uint(pp[kt][3]), __float_as_uint(pp[kt][2]), 0x07060302u);
                    *(uint2*)&Ps[wave][qt * 16 + lc][kt * 16 + lg * 4] = w;
                }
            }
            asm volatile("s_waitcnt lgkmcnt(0)" ::: "memory");

            // ---- O^T += V^T P^T : 16 MFMA, vtf shared across q-tiles ----
            bf16x8 pf[2][2];
#pragma unroll
            for (int qt = 0; qt < 2; ++qt)
#pragma unroll
                for (int c = 0; c < 2; ++c)
                    pf[qt][c] = *(const bf16x8*)&Ps[wave][qt * 16 + lc][c * 32 + lg * 8];
            __builtin_amdgcn_s_setprio(1);
#pragma unroll
            for (int dt = 0; dt < 4; ++dt)
#pragma unroll
                for (int c = 0; c < 2; ++c) {
                    bf16x8 vtf = *(const bf16x8*)&VTs[cur][dt * 16 + lc][((4 * c + lg) ^ lc7) * 8];
#pragma unroll
                    for (int qt = 0; qt < 2; ++qt)
                        oacc[qt][dt] = MFMA16(vtf, pf[qt][c], oacc[qt][dt]);
                }
            __builtin_amdgcn_s_setprio(0);
        }

        // write next tile into the other buffer (pack K fp32->bf16 here)
        if (havenext) {
            union { uint2 u[2]; bf16x8 v; } cka, ckb;
            cka.u[0] = pack4_rhu(nka0);
            cka.u[1] = pack4_rhu(nka1);
            ckb.u[0] = pack4_rhu(nkb0);
            ckb.u[1] = pack4_rhu(nkb1);
            *(bf16x8*)&Ks[cur ^ 1][r0][swz]       = cka.v;
            *(bf16x8*)&Ks[cur ^ 1][r0 + 32][swz]  = ckb.v;
            *(bf16x8*)&VTs[cur ^ 1][r0][swz]      = nv0;
            *(bf16x8*)&VTs[cur ^ 1][r0 + 32][swz] = nv1;
        }
        cur ^= 1;
    }

    // epilogue: finish l reduction, normalize, add residual, vec4 store
#pragma unroll
    for (int qt = 0; qt < 2; ++qt) {
        float lt = l_r[qt];
        lt += __shfl_xor(lt, 16, 64);
        lt += __shfl_xor(lt, 32, 64);
        float li = 1.0f / lt;
        const int q = qw0 + qt * 16 + lc;
        const size_t obase = ((size_t)b * 2048 + q) * 1024 + (size_t)h * 64 + lg * 4;
#pragma unroll
        for (int dt = 0; dt < 4; ++dt) {
            const size_t oi = obase + dt * 16;
            float4 xv = *(const float4*)(x + oi);
            float4 ov;
            ov.x = xv.x + oacc[qt][dt][0] * li;
            ov.y = xv.y + oacc[qt][dt][1] * li;
            ov.z = xv.z + oacc[qt][dt][2] * li;
            ov.w = xv.w + oacc[qt][dt][3] * li;
            *(float4*)(outp + oi) = ov;
        }
    }
}

extern "C" void kernel_launch(void* const* d_in, const int* in_sizes, int n_in,
                              void* d_out, int out_size, void* d_ws, size_t ws_size,
                              hipStream_t stream) {
    const float* x  = (const float*)d_in[0];
    const float* k  = (const float*)d_in[1];
    const float* v  = (const float*)d_in[2];
    const float* wq = (const float*)d_in[3];
    float* outp = (float*)d_out;

    const size_t NELEM = (size_t)4 * 2048 * 1024;
    unsigned short* qbuf  = (unsigned short*)d_ws;
    unsigned short* vtbuf = qbuf + NELEM;

    // merged prep: 512 qproj + 2048 v-trans (k-conversion eliminated)
    prep_kernel<<<512 + 2048, 256, 0, stream>>>(x, wq, v, qbuf, vtbuf);
    attn_kernel<<<dim3(64, 16), 256, 0, stream>>>(qbuf, k, vtbuf, x, outp);
}